// Round 15
// baseline (404.760 us; speedup 1.0000x reference)
//
#include <hip/hip_runtime.h>
#include <hip/hip_bf16.h>
#include <stdint.h>

#define DEVI __device__ __forceinline__

static constexpr int Bn = 8, Ln = 128;
static constexpr int EMBc = 300, POSc = 30, INc = 330;
static constexpr int KPAD = 384;
static constexpr int Hc = 256, H2c = 512, G4 = 1024, G3 = 1536;
static constexpr int G2 = 2048;
static constexpr int GHW = 3072;
static constexpr int NBIOc = 9, NLABc = 10;
static constexpr float NEGc = -100000000000.0f;

typedef __attribute__((ext_vector_type(8))) short bf16x8;
typedef __attribute__((ext_vector_type(4))) float f32x4;

DEVI float sigf(float x) { return 1.0f / (1.0f + __expf(-x)); }

DEVI unsigned short b16rne(float f) {
    union { float f; unsigned u; } v; v.f = f;
    unsigned u = v.u;
    return (unsigned short)((u + 0x7FFFu + ((u >> 16) & 1u)) >> 16);
}

// ---------------- prep0: embed->bf16 x, WihFB_bf, biasFB, + zero hG exchange buf ----------------
__global__ void k_prep0(const int* __restrict__ tok, const int* __restrict__ pos,
                        const float* __restrict__ emb, const float* __restrict__ pemb,
                        const float* __restrict__ WihF, const float* __restrict__ WihB,
                        const float* __restrict__ bF, const float* __restrict__ bB,
                        ushort* __restrict__ x, ushort* __restrict__ WihFB,
                        float* __restrict__ biasFB, uint32_t* __restrict__ hG32) {
    int i = blockIdx.x * 256 + threadIdx.x;
    const int N0 = Bn * Ln * KPAD;
    const int N1 = N0 + G2 * KPAD;
    const int N2 = N1 + G2;
    const int N3 = N2 + 8192;
    if (i < N0) {
        int bl = i / KPAD, c = i - bl * KPAD;
        float v = 0.f;
        if (c < EMBc) v = emb[tok[bl] * EMBc + c];
        else if (c < INc) v = pemb[pos[bl] * POSc + (c - EMBc)];
        x[i] = b16rne(v);
    } else if (i < N1) {
        int w = i - N0;
        int r = w / KPAD, c = w - r * KPAD;
        float v = 0.f;
        if (c < INc) v = (r < G4) ? WihF[(size_t)r * INc + c] : WihB[(size_t)(r - G4) * INc + c];
        WihFB[w] = b16rne(v);
    } else if (i < N2) {
        int j = i - N1;
        biasFB[j] = (j < G4) ? bF[j] : bB[j - G4];
    } else if (i < N3) {
        __hip_atomic_store(&hG32[i - N2], 0u, __ATOMIC_RELAXED, __HIP_MEMORY_SCOPE_AGENT);
    }
}

// ---------------- shared 64x64 MFMA GEMM tile body ----------------
DEVI void gemm_tile(const ushort* __restrict__ A, const ushort* __restrict__ B,
                    const float* __restrict__ bias, float* __restrict__ C,
                    int N, int K, int m0, int n0,
                    ushort (*As)[72], ushort (*Bs)[72]) {
    int tid = threadIdx.x;
    int lane = tid & 63, wv = tid >> 6;
    int mw = (wv >> 1) * 32, nw = (wv & 1) * 32;
    int lr16 = lane & 15, g4 = lane >> 4;
    f32x4 acc[2][2] = {};
    for (int k0 = 0; k0 < K; k0 += 64) {
#pragma unroll
        for (int it = 0; it < 2; it++) {
            int idx = tid + it * 256;
            int r = idx >> 3, ch = idx & 7;
            uint4 av = *(const uint4*)(A + (size_t)(m0 + r) * K + k0 + ch * 8);
            *(uint4*)(&As[r][ch * 8]) = av;
            uint4 bv2 = *(const uint4*)(B + (size_t)(n0 + r) * K + k0 + ch * 8);
            *(uint4*)(&Bs[r][ch * 8]) = bv2;
        }
        __syncthreads();
#pragma unroll
        for (int ks = 0; ks < 2; ks++) {
            bf16x8 af[2], bfr[2];
#pragma unroll
            for (int i = 0; i < 2; i++) {
                af[i]  = *(const bf16x8*)(&As[mw + i * 16 + lr16][ks * 32 + g4 * 8]);
                bfr[i] = *(const bf16x8*)(&Bs[nw + i * 16 + lr16][ks * 32 + g4 * 8]);
            }
#pragma unroll
            for (int i = 0; i < 2; i++)
#pragma unroll
                for (int j = 0; j < 2; j++)
                    acc[i][j] = __builtin_amdgcn_mfma_f32_16x16x32_bf16(af[i], bfr[j], acc[i][j], 0, 0, 0);
        }
        __syncthreads();
    }
#pragma unroll
    for (int i = 0; i < 2; i++)
#pragma unroll
        for (int j = 0; j < 2; j++)
#pragma unroll
            for (int r2 = 0; r2 < 4; r2++) {
                int mm = m0 + mw + i * 16 + g4 * 4 + r2;
                int nn = n0 + nw + j * 16 + lr16;
                C[(size_t)mm * N + nn] = acc[i][j][r2] + (bias ? bias[nn] : 0.f);
            }
}

// ---------------- input projection GEMM (0-511) + round-weight prep (512-639) ----------------
__global__ __launch_bounds__(256) void k_xproj(
    const ushort* __restrict__ x_bf, const ushort* __restrict__ WihFB,
    const float* __restrict__ biasFB, float* __restrict__ Xpre,
    const float* __restrict__ Wg_hh, const float* __restrict__ Wr_hh,
    const float* __restrict__ W_Lr, const float* __restrict__ bg_hh,
    const float* __restrict__ br_hh,
    const float* __restrict__ Wg_ih, const float* __restrict__ Wr_ih,
    ushort* __restrict__ WhhGR, ushort* __restrict__ WLrAB, float* __restrict__ biasGR,
    float* __restrict__ WgihT, float* __restrict__ WrihT) {
    int bid = blockIdx.x;
    __shared__ __align__(16) ushort As[64][72];
    __shared__ __align__(16) ushort Bs[64][72];
    if (bid < 512) {
        int nt = bid & 31, mt = bid >> 5;
        gemm_tile(x_bf, WihFB, biasFB, Xpre, G2, KPAD, mt * 64, nt * 64, As, Bs);
        return;
    }
    const int stride = 128 * 256;
    int pid = (bid - 512) * 256 + threadIdx.x;
    for (int idx = pid; idx < GHW * H2c; idx += stride) {
        int r = idx >> 9, c = idx & 511;
        float v = (r < G3) ? Wg_hh[(size_t)r * H2c + c] : Wr_hh[(size_t)(r - G3) * H2c + c];
        WhhGR[idx] = b16rne(v);
    }
    for (int idx = pid; idx < G4 * H2c; idx += stride) {
        int r = idx >> 9, c = idx & 511;
        float v = (r < H2c) ? W_Lr[(size_t)r * (2 * H2c) + c]
                            : W_Lr[(size_t)(r - H2c) * (2 * H2c) + H2c + c];
        WLrAB[idx] = b16rne(v);
    }
    for (int idx = pid; idx < GHW; idx += stride)
        biasGR[idx] = (idx < G3) ? bg_hh[idx] : br_hh[idx - G3];
    for (int idx = pid; idx < NBIOc * G3; idx += stride) {
        int k = idx / G3, rj = idx - k * G3;
        WgihT[idx] = Wg_ih[(size_t)rj * NBIOc + k];
    }
    for (int idx = pid; idx < NLABc * G3; idx += stride) {
        int k = idx / G3, rj = idx - k * G3;
        WrihT[idx] = Wr_ih[(size_t)rj * NLABc + k];
    }
}

// ---------------- bidirectional masked LSTM (8 blocks x 512 threads) ----------------
// r11 structure + own-half LDS-direct: publish writes own pair straight into the
// next-step LDS buffer; polls cover ONLY the 768 partner units (threads 0-255
// poll 2, 256-511 poll 1 — wave-uniform). hlds[0] own entries zeroed pre-loop.
__global__ __launch_bounds__(512) void k_lstm_mfma(
    const float* __restrict__ Xpre, const float* __restrict__ WhhF,
    const float* __restrict__ WhhB, const float* __restrict__ mask,
    float* __restrict__ Henc, ushort* __restrict__ HencB,
    unsigned long long* __restrict__ hG) {
    const int blk = blockIdx.x;
    const int d = blk >> 2, q = blk & 3;
    const float* Whh = d ? WhhB : WhhF;
    const int tid = threadIdx.x;
    const int lane = tid & 63, wv = tid >> 6;
    const int lr16 = lane & 15, g4 = lane >> 4;

    __shared__ __align__(16) uint32_t hlds[2][8 * 136];
    __shared__ float Glds[256][9];

    bf16x8 aw[16];
#pragma unroll
    for (int jt2 = 0; jt2 < 2; jt2++) {
        int jt = wv * 2 + jt2;
        int lr = jt * 16 + lr16;
        int g = lr >> 6, jj = lr & 63;
        int R = g * 256 + q * 64 + jj;
        const float* wr = Whh + (size_t)R * 256;
#pragma unroll
        for (int kt = 0; kt < 8; kt++) {
            int k0 = kt * 32 + g4 * 8;
            float4 f0 = *(const float4*)(wr + k0);
            float4 f1 = *(const float4*)(wr + k0 + 4);
            bf16x8 a;
            a[0] = (short)b16rne(f0.x); a[1] = (short)b16rne(f0.y);
            a[2] = (short)b16rne(f0.z); a[3] = (short)b16rne(f0.w);
            a[4] = (short)b16rne(f1.x); a[5] = (short)b16rne(f1.y);
            a[6] = (short)b16rne(f1.z); a[7] = (short)b16rne(f1.w);
            aw[jt2 * 8 + kt] = a;
        }
    }

    const int jj_t = tid & 63, b_t = tid >> 6;
    float hval = 0.f, cval = 0.f;
    const int bcol = lane & 15;
    const int bb = lane & 7;

    // partner-q list (the 3 q' != q)
    int qm0, qm1, qm2;
    { int c = 0, tmp[3];
      for (int qq = 0; qq < 4; qq++) if (qq != q) tmp[c++] = qq;
      qm0 = tmp[0]; qm1 = tmp[1]; qm2 = tmp[2]; }
    auto qmap = [&](int idx3) { return idx3 == 0 ? qm0 : (idx3 == 1 ? qm1 : qm2); };

    // poll units: pu0 = tid (0..511), pu1 = tid + 512 (valid if tid < 256)
    const int pu0 = tid;
    const int b0 = pu0 / 96, r0 = pu0 % 96;
    const int u0 = b0 * 128 + qmap(r0 >> 5) * 32 + (r0 & 31);
    const int l0 = b0 * 136 + qmap(r0 >> 5) * 32 + (r0 & 31);
    const bool have1 = tid < 256;
    int u1 = 0, l1 = 0;
    if (have1) {
        int pu1 = tid + 512;
        int b1 = pu1 / 96, r1 = pu1 % 96;
        u1 = b1 * 128 + qmap(r1 >> 5) * 32 + (r1 & 31);
        l1 = b1 * 136 + qmap(r1 >> 5) * 32 + (r1 & 31);
    }

    // zero step-0 buffer (h0 = 0): own entries needed; partner entries harmless
    for (int i = tid; i < 8 * 136; i += 512) hlds[0][i] = 0u;
    // ordered before step-0 reads by barrier A

    for (int s = 0; s < Ln; s++) {
        const int t = d ? (Ln - 1 - s) : s;

        const float* xrow = Xpre + ((size_t)(b_t * Ln + t)) * G2 + d * G4 + q * 64 + jj_t;
        float xg0 = xrow[0], xg1 = xrow[256], xg2 = xrow[512], xg3 = xrow[768];
        float mval = mask[b_t * Ln + t];

        // ---- poll the 768 partner units only ----
        uint32_t* hb = hlds[s & 1];
        {
            const unsigned long long* slot = hG + ((size_t)(s & 1) * 2 + d) * 1024;
            unsigned long long ea, eb = 0;
            do {
                ea = __hip_atomic_load(slot + u0, __ATOMIC_RELAXED, __HIP_MEMORY_SCOPE_AGENT);
                if (have1)
                    eb = __hip_atomic_load(slot + u1, __ATOMIC_RELAXED, __HIP_MEMORY_SCOPE_AGENT);
            } while ((unsigned)(ea >> 32) != (unsigned)s ||
                     (have1 && (unsigned)(eb >> 32) != (unsigned)s));
            hb[l0] = (uint32_t)ea;
            if (have1) hb[l1] = (uint32_t)eb;
        }
        __syncthreads();                          // A: stage-write -> ds_read

        bf16x8 bv[8];
#pragma unroll
        for (int kt = 0; kt < 8; kt++)
            bv[kt] = *(const bf16x8*)(&hb[bb * 136 + kt * 16 + g4 * 4]);

        f32x4 acc0 = {0.f, 0.f, 0.f, 0.f}, acc1 = {0.f, 0.f, 0.f, 0.f};
#pragma unroll
        for (int kt = 0; kt < 8; kt++) {
            acc0 = __builtin_amdgcn_mfma_f32_16x16x32_bf16(aw[kt], bv[kt], acc0, 0, 0, 0);
            acc1 = __builtin_amdgcn_mfma_f32_16x16x32_bf16(aw[8 + kt], bv[kt], acc1, 0, 0, 0);
        }

        if (bcol < 8) {
            int lrb0 = (wv * 2 + 0) * 16 + g4 * 4;
            int lrb1 = (wv * 2 + 1) * 16 + g4 * 4;
#pragma unroll
            for (int r2 = 0; r2 < 4; r2++) Glds[lrb0 + r2][bcol] = acc0[r2];
#pragma unroll
            for (int r2 = 0; r2 < 4; r2++) Glds[lrb1 + r2][bcol] = acc1[r2];
        }
        __syncthreads();                          // B: Glds write -> read

        float iv = sigf(xg0 + Glds[jj_t][b_t]);
        float fv = sigf(xg1 + Glds[64 + jj_t][b_t]);
        float gv = tanhf(xg2 + Glds[128 + jj_t][b_t]);
        float ov = sigf(xg3 + Glds[192 + jj_t][b_t]);
        float cn = fv * cval + iv * gv;
        float hn = ov * tanhf(cn);
        float hv = mval * hn + (1.f - mval) * hval;
        cval = mval * cn + (1.f - mval) * cval;
        hval = hv;

        // publish FIRST (IC, for partners) + own pair straight into next-step LDS
        int hbits = (int)b16rne(hv);
        int pbits = __shfl_xor(hbits, 1);
        if ((jj_t & 1) == 0) {
            uint32_t dataw = ((uint32_t)hbits & 0xFFFFu) | ((uint32_t)pbits << 16);
            unsigned long long word = ((unsigned long long)(unsigned)(s + 1) << 32) | dataw;
            __hip_atomic_store(hG + ((size_t)((s + 1) & 1) * 2 + d) * 1024 +
                                   b_t * 128 + q * 32 + (jj_t >> 1),
                               word, __ATOMIC_RELAXED, __HIP_MEMORY_SCOPE_AGENT);
            hlds[(s + 1) & 1][b_t * 136 + q * 32 + (jj_t >> 1)] = dataw;
        }
        float ho = hv * mval;
        size_t hidx = ((size_t)(b_t * Ln + t)) * H2c + d * Hc + q * 64 + jj_t;
        Henc[hidx] = ho;
        HencB[hidx] = b16rne(ho);
        __syncthreads();                          // C: drain publishes before next poll
    }
}

// ---------------- mega: gh GEMM (0..nGh) | pairC GEMM (+256) | proj9 (+256) ----------------
__global__ __launch_bounds__(256) void k_mega(
    int nGh,
    const ushort* __restrict__ Agh, const ushort* __restrict__ Bgh,
    const float* __restrict__ biasGh, float* __restrict__ Cgh,
    const ushort* __restrict__ Apc, const ushort* __restrict__ Bpc,
    float* __restrict__ Cpc,
    const float* __restrict__ Hp9, const float* __restrict__ W9,
    const float* __restrict__ b9, float* __restrict__ out9) {
    int bid = blockIdx.x;
    __shared__ __align__(16) ushort As[64][72];
    __shared__ __align__(16) ushort Bs[64][72];
    if (bid < nGh) {
        int nt = bid % 48, mt = bid / 48;
        gemm_tile(Agh, Bgh, biasGh, Cgh, GHW, H2c, mt * 64, nt * 64, As, Bs);
    } else if (bid < nGh + 256) {
        int b2 = bid - nGh;
        int nt = b2 & 15, mt = b2 >> 4;
        gemm_tile(Apc, Bpc, nullptr, Cpc, G4, H2c, mt * 64, nt * 64, As, Bs);
    } else {
        int b3 = bid - nGh - 256;
        int lane = threadIdx.x & 63, wvv = threadIdx.x >> 6;
        int row = b3 * 4 + wvv;
        const float4* h4 = (const float4*)(Hp9 + (size_t)row * H2c + lane * 8);
        float4 h0 = h4[0], h1 = h4[1];
        float acc[NBIOc];
#pragma unroll
        for (int k = 0; k < NBIOc; k++) {
            const float4* w4 = (const float4*)(W9 + (size_t)k * H2c + lane * 8);
            float4 w0 = w4[0], w1 = w4[1];
            acc[k] = h0.x * w0.x + h0.y * w0.y + h0.z * w0.z + h0.w * w0.w +
                     h1.x * w1.x + h1.y * w1.y + h1.z * w1.z + h1.w * w1.w;
        }
#pragma unroll
        for (int off = 32; off >= 1; off >>= 1)
#pragma unroll
            for (int k = 0; k < NBIOc; k++) acc[k] += __shfl_down(acc[k], off);
        if (lane == 0) {
#pragma unroll
            for (int k = 0; k < NBIOc; k++) out9[(size_t)row * NBIOc + k] = acc[k] + b9[k];
        }
    }
}

// ---------------- fused pairmax + double GRU per row m (transposed ih weights) ----------------
__global__ __launch_bounds__(128) void k_pairgru(
    const float* __restrict__ Cp, const float* __restrict__ bL,
    const float* __restrict__ WCr, const float* __restrict__ bCr,
    const float* __restrict__ mask, const float* __restrict__ cg,
    const float* __restrict__ gh,
    const float* __restrict__ WgihT, const float* __restrict__ bg_ih,
    const float* __restrict__ WrihT, const float* __restrict__ br_ih,
    const float* __restrict__ hprev,
    float* __restrict__ Hg_out, float* __restrict__ Hcb_out,
    ushort* __restrict__ Hrb_out, ushort* __restrict__ Hcbb_out) {
    int m = blockIdx.x;
    int b = m >> 7;
    __shared__ __align__(16) float As[H2c];
    __shared__ __align__(16) float Ws[NLABc][H2c];
    __shared__ float red[NLABc][128];
    __shared__ float pCr_s[NLABc];
    int tid = threadIdx.x;
    for (int i = tid; i < H2c; i += 128) As[i] = Cp[(size_t)m * G4 + i] + bL[i];
    for (int i = tid; i < NLABc * H2c; i += 128) Ws[i / H2c][i % H2c] = WCr[i];
    __syncthreads();
    {
        int t = tid;
        float m3 = mask[m] * mask[b * Ln + t];
        float outv[NLABc];
        if (m3 > 0.f) {
            float4 acc[NLABc];
#pragma unroll
            for (int k = 0; k < NLABc; k++) acc[k] = make_float4(0.f, 0.f, 0.f, 0.f);
            const float4* B4 = (const float4*)(Cp + (size_t)(b * Ln + t) * G4 + H2c);
            const float4* A4 = (const float4*)As;
            for (int qq = 0; qq < H2c / 4; qq++) {
                float4 a = A4[qq], bb = B4[qq];
                float4 e;
                e.x = fmaxf(a.x + bb.x, 0.f);
                e.y = fmaxf(a.y + bb.y, 0.f);
                e.z = fmaxf(a.z + bb.z, 0.f);
                e.w = fmaxf(a.w + bb.w, 0.f);
#pragma unroll
                for (int k = 0; k < NLABc; k++) {
                    float4 w = *(const float4*)(&Ws[k][qq * 4]);
                    acc[k].x += e.x * w.x; acc[k].y += e.y * w.y;
                    acc[k].z += e.z * w.z; acc[k].w += e.w * w.w;
                }
            }
#pragma unroll
            for (int k = 0; k < NLABc; k++)
                outv[k] = sigf(acc[k].x + acc[k].y + acc[k].z + acc[k].w + bCr[k]);
        } else {
#pragma unroll
            for (int k = 0; k < NLABc; k++) outv[k] = NEGc;
        }
#pragma unroll
        for (int k = 0; k < NLABc; k++) red[k][tid] = outv[k];
    }
    __syncthreads();
    for (int off = 64; off >= 1; off >>= 1) {
        if (tid < off) {
#pragma unroll
            for (int k = 0; k < NLABc; k++) red[k][tid] = fmaxf(red[k][tid], red[k][tid + off]);
        }
        __syncthreads();
    }
    if (tid < NLABc) pCr_s[tid] = red[tid][0];
    __syncthreads();

    float v[NBIOc], mx = -3.4e38f;
#pragma unroll
    for (int k = 0; k < NBIOc; k++) { v[k] = cg[m * NBIOc + k]; mx = fmaxf(mx, v[k]); }
    float ssum = 0.f;
#pragma unroll
    for (int k = 0; k < NBIOc; k++) { v[k] = __expf(v[k] - mx); ssum += v[k]; }
    float inv = 1.f / ssum;
#pragma unroll
    for (int k = 0; k < NBIOc; k++) v[k] *= inv;

    const float* g1b = gh + (size_t)m * GHW;
#pragma unroll
    for (int u = 0; u < 4; u++) {
        int j = tid + u * 128;
        size_t i = (size_t)m * H2c + j;

        float gr = bg_ih[j], gz = bg_ih[H2c + j], gn = bg_ih[2 * H2c + j];
#pragma unroll
        for (int k = 0; k < NBIOc; k++) {
            float pv = v[k];
            gr += WgihT[k * G3 + j] * pv;
            gz += WgihT[k * G3 + H2c + j] * pv;
            gn += WgihT[k * G3 + 2 * H2c + j] * pv;
        }
        float hp = hprev[i];
        float r1 = sigf(gr + g1b[j]);
        float z1 = sigf(gz + g1b[H2c + j]);
        float n1 = tanhf(gn + r1 * g1b[2 * H2c + j]);
        float hg = (1.f - z1) * n1 + z1 * hp;

        float rr = br_ih[j], rz = br_ih[H2c + j], rn = br_ih[2 * H2c + j];
#pragma unroll
        for (int k = 0; k < NLABc; k++) {
            float pv = pCr_s[k];
            rr += WrihT[k * G3 + j] * pv;
            rz += WrihT[k * G3 + H2c + j] * pv;
            rn += WrihT[k * G3 + 2 * H2c + j] * pv;
        }
        const float* g2b = g1b + G3;
        float r2 = sigf(rr + g2b[j]);
        float z2 = sigf(rz + g2b[H2c + j]);
        float n2 = tanhf(rn + r2 * g2b[2 * H2c + j]);
        float hr = (1.f - z2) * n2 + z2 * hp;

        float hc = hp + hr + hg;
        Hg_out[i] = hg;
        Hcb_out[i] = hc;
        Hrb_out[i] = b16rne(hr);
        Hcbb_out[i] = b16rne(hc);
    }
}

// ---------------- final: pairfull (blocks 0-1023) + log_softmax (blocks 1024-1031) ----------------
__global__ __launch_bounds__(128) void k_final_out(
    const float* __restrict__ Cp, const float* __restrict__ bL,
    const float* __restrict__ WCr, const float* __restrict__ bCr,
    const float* __restrict__ mask, const float* __restrict__ cg,
    float* __restrict__ outp) {
    int bid = blockIdx.x;
    int tid = threadIdx.x;
    if (bid >= Bn * Ln) {
        int r = (bid - Bn * Ln) * 128 + tid;
        float v[NBIOc], mx = -3.4e38f;
#pragma unroll
        for (int k = 0; k < NBIOc; k++) { v[k] = cg[r * NBIOc + k]; mx = fmaxf(mx, v[k]); }
        float s = 0.f;
#pragma unroll
        for (int k = 0; k < NBIOc; k++) s += __expf(v[k] - mx);
        float lse = mx + __logf(s);
        float m = mask[r];
#pragma unroll
        for (int k = 0; k < NBIOc; k++) outp[r * NBIOc + k] = (v[k] - lse) * m;
        return;
    }
    int bs = bid;
    int b = bs >> 7;
    __shared__ __align__(16) float As[H2c];
    __shared__ __align__(16) float Ws[NLABc][H2c];
    for (int i = tid; i < H2c; i += 128) As[i] = Cp[(size_t)bs * G4 + i] + bL[i];
    for (int i = tid; i < NLABc * H2c; i += 128) Ws[i / H2c][i % H2c] = WCr[i];
    __syncthreads();
    int t = tid;
    float m3 = mask[bs] * mask[b * Ln + t];
    float outv[NLABc];
    if (m3 > 0.f) {
        float4 acc[NLABc];
#pragma unroll
        for (int k = 0; k < NLABc; k++) acc[k] = make_float4(0.f, 0.f, 0.f, 0.f);
        const float4* B4 = (const float4*)(Cp + (size_t)(b * Ln + t) * G4 + H2c);
        const float4* A4 = (const float4*)As;
        for (int qq = 0; qq < H2c / 4; qq++) {
            float4 a = A4[qq], bb = B4[qq];
            float4 e;
            e.x = fmaxf(a.x + bb.x, 0.f);
            e.y = fmaxf(a.y + bb.y, 0.f);
            e.z = fmaxf(a.z + bb.z, 0.f);
            e.w = fmaxf(a.w + bb.w, 0.f);
#pragma unroll
            for (int k = 0; k < NLABc; k++) {
                float4 w = *(const float4*)(&Ws[k][qq * 4]);
                acc[k].x += e.x * w.x; acc[k].y += e.y * w.y;
                acc[k].z += e.z * w.z; acc[k].w += e.w * w.w;
            }
        }
#pragma unroll
        for (int k = 0; k < NLABc; k++)
            outv[k] = sigf(acc[k].x + acc[k].y + acc[k].z + acc[k].w + bCr[k]);
    } else {
#pragma unroll
        for (int k = 0; k < NLABc; k++) outv[k] = 0.f;
    }
    size_t base = (size_t)(Bn * Ln * NBIOc) + ((size_t)bs * Ln + t) * NLABc;
#pragma unroll
    for (int k = 0; k < NLABc; k++) outp[base + k] = outv[k];
}

extern "C" void kernel_launch(void* const* d_in, const int* in_sizes, int n_in,
                              void* d_out, int out_size, void* d_ws, size_t ws_size,
                              hipStream_t stream) {
    const int*   tok   = (const int*)d_in[0];
    const int*   pos   = (const int*)d_in[1];
    const float* mask  = (const float*)d_in[2];
    const float* emb   = (const float*)d_in[3];
    const float* pemb  = (const float*)d_in[4];
    const float* WihF  = (const float*)d_in[5];
    const float* WhhF  = (const float*)d_in[6];
    const float* bF    = (const float*)d_in[7];
    const float* WihB  = (const float*)d_in[8];
    const float* WhhB  = (const float*)d_in[9];
    const float* bB    = (const float*)d_in[10];
    const float* Wg_ih = (const float*)d_in[11];
    const float* Wg_hh = (const float*)d_in[12];
    const float* bg_ih = (const float*)d_in[13];
    const float* bg_hh = (const float*)d_in[14];
    const float* Wr_ih = (const float*)d_in[15];
    const float* Wr_hh = (const float*)d_in[16];
    const float* br_ih = (const float*)d_in[17];
    const float* br_hh = (const float*)d_in[18];
    const float* W_Lr  = (const float*)d_in[19];
    const float* b_Lr  = (const float*)d_in[20];
    const float* W_Cr  = (const float*)d_in[21];
    const float* b_Cr  = (const float*)d_in[22];
    const float* W_Cg  = (const float*)d_in[23];
    const float* b_Cg  = (const float*)d_in[24];

    float* outp = (float*)d_out;
    float* ws = (float*)d_ws;

    unsigned long long* hG = (unsigned long long*)ws;
    size_t off = 8192;
    auto alloc = [&](size_t n) { off = (off + 3) & ~(size_t)3; float* p = ws + off; off += n; return p; };
    auto allocU = [&](size_t n_us) { off = (off + 3) & ~(size_t)3; ushort* p = (ushort*)(ws + off); off += (n_us + 1) / 2; return p; };

    float* R1 = alloc((size_t)G4 * GHW);
    float* Xpre = R1;
    float* gh   = R1;
    ushort* WihFB_bf = (ushort*)(R1 + (size_t)G4 * G2);
    ushort* x_bf     = (ushort*)(R1 + (size_t)G4 * G2 + 393216);
    float*  biasFB   = R1 + (size_t)G4 * G2 + 393216 + 196608;

    float*  pairC    = alloc((size_t)G4 * G4);
    ushort* WhhGR_bf = allocU((size_t)GHW * H2c);
    ushort* WLrAB_bf = allocU((size_t)G4 * H2c);
    float*  biasGR   = alloc(GHW);
    float*  WgihT    = alloc((size_t)NBIOc * G3);
    float*  WrihT    = alloc((size_t)NLABc * G3);
    float*  Henc     = alloc((size_t)Bn * Ln * H2c);
    ushort* Henc_bf  = allocU((size_t)Bn * Ln * H2c);
    float*  Hg       = alloc((size_t)Bn * Ln * H2c);
    float*  Hcb      = alloc((size_t)Bn * Ln * H2c);
    ushort* Hr_bf    = allocU((size_t)Bn * Ln * H2c);
    ushort* Hcb_bf   = allocU((size_t)Bn * Ln * H2c);
    float*  cg       = alloc((size_t)Bn * Ln * NBIOc);
    (void)ws_size; (void)in_sizes; (void)n_in; (void)out_size;

    // --- prep0: embed + input-proj weights + zero hG (agent-scope stores) ---
    {
        int total = Bn * Ln * KPAD + G2 * KPAD + G2 + 8192;
        k_prep0<<<(total + 255) / 256, 256, 0, stream>>>(
            tok, pos, emb, pemb, WihF, WihB, bF, bB, x_bf, WihFB_bf, biasFB,
            (uint32_t*)hG);
    }

    // --- input projection GEMM + concurrent round-weight prep ---
    k_xproj<<<640, 256, 0, stream>>>(x_bf, WihFB_bf, biasFB, Xpre,
                                     Wg_hh, Wr_hh, W_Lr, bg_hh, br_hh,
                                     Wg_ih, Wr_ih,
                                     WhhGR_bf, WLrAB_bf, biasGR, WgihT, WrihT);

    // --- bidirectional LSTM: 8 blocks x 512 threads ---
    k_lstm_mfma<<<8, 512, 0, stream>>>(Xpre, WhhF, WhhB, mask, Henc, Henc_bf, hG);

    // --- message-passing rounds ---
    const float*  Hgs    = Henc;
    const ushort* Hrs_bf = Henc_bf;
    const float*  Hcs    = Henc;
    const ushort* Hcs_bf = Henc_bf;
    for (int r = 0; r < 2; r++) {
        k_mega<<<768 + 512, 256, 0, stream>>>(768,
            Hcs_bf, WhhGR_bf, biasGR, gh,
            Hrs_bf, WLrAB_bf, pairC,
            Hgs, W_Cg, b_Cg, cg);
        k_pairgru<<<Bn * Ln, 128, 0, stream>>>(
            pairC, b_Lr, W_Cr, b_Cr, mask, cg, gh,
            WgihT, bg_ih, WrihT, br_ih, Hcs,
            Hg, Hcb, Hr_bf, Hcb_bf);
        Hgs = Hg; Hrs_bf = Hr_bf; Hcs = Hcb; Hcs_bf = Hcb_bf;
    }

    // --- final outputs: pairC GEMM + proj9, then pairfull + logsoftmax ---
    k_mega<<<512, 256, 0, stream>>>(0,
        nullptr, nullptr, nullptr, nullptr,
        Hrs_bf, WLrAB_bf, pairC,
        Hgs, W_Cg, b_Cg, cg);
    k_final_out<<<Bn * Ln + 8, 128, 0, stream>>>(pairC, b_Lr, W_Cr, b_Cr, mask, cg, outp);
}

// Round 16
// 398.862 us; speedup vs baseline: 1.0148x; 1.0148x over previous
//
#include <hip/hip_runtime.h>
#include <hip/hip_bf16.h>
#include <stdint.h>

#define DEVI __device__ __forceinline__

static constexpr int Bn = 8, Ln = 128;
static constexpr int EMBc = 300, POSc = 30, INc = 330;
static constexpr int KPAD = 384;
static constexpr int Hc = 256, H2c = 512, G4 = 1024, G3 = 1536;
static constexpr int G2 = 2048;
static constexpr int GHW = 3072;
static constexpr int NBIOc = 9, NLABc = 10;
static constexpr float NEGc = -100000000000.0f;

typedef __attribute__((ext_vector_type(8))) short bf16x8;
typedef __attribute__((ext_vector_type(4))) float f32x4;

DEVI float sigf(float x) { return 1.0f / (1.0f + __expf(-x)); }

DEVI unsigned short b16rne(float f) {
    union { float f; unsigned u; } v; v.f = f;
    unsigned u = v.u;
    return (unsigned short)((u + 0x7FFFu + ((u >> 16) & 1u)) >> 16);
}

// ---------------- prep0: embed->bf16 x, WihFB_bf, biasFB, + zero hG exchange buf ----------------
__global__ void k_prep0(const int* __restrict__ tok, const int* __restrict__ pos,
                        const float* __restrict__ emb, const float* __restrict__ pemb,
                        const float* __restrict__ WihF, const float* __restrict__ WihB,
                        const float* __restrict__ bF, const float* __restrict__ bB,
                        ushort* __restrict__ x, ushort* __restrict__ WihFB,
                        float* __restrict__ biasFB, uint32_t* __restrict__ hG32) {
    int i = blockIdx.x * 256 + threadIdx.x;
    const int N0 = Bn * Ln * KPAD;
    const int N1 = N0 + G2 * KPAD;
    const int N2 = N1 + G2;
    const int N3 = N2 + 8192;
    if (i < N0) {
        int bl = i / KPAD, c = i - bl * KPAD;
        float v = 0.f;
        if (c < EMBc) v = emb[tok[bl] * EMBc + c];
        else if (c < INc) v = pemb[pos[bl] * POSc + (c - EMBc)];
        x[i] = b16rne(v);
    } else if (i < N1) {
        int w = i - N0;
        int r = w / KPAD, c = w - r * KPAD;
        float v = 0.f;
        if (c < INc) v = (r < G4) ? WihF[(size_t)r * INc + c] : WihB[(size_t)(r - G4) * INc + c];
        WihFB[w] = b16rne(v);
    } else if (i < N2) {
        int j = i - N1;
        biasFB[j] = (j < G4) ? bF[j] : bB[j - G4];
    } else if (i < N3) {
        __hip_atomic_store(&hG32[i - N2], 0u, __ATOMIC_RELAXED, __HIP_MEMORY_SCOPE_AGENT);
    }
}

// ---------------- shared 64x64 MFMA GEMM tile body ----------------
DEVI void gemm_tile(const ushort* __restrict__ A, const ushort* __restrict__ B,
                    const float* __restrict__ bias, float* __restrict__ C,
                    int N, int K, int m0, int n0,
                    ushort (*As)[72], ushort (*Bs)[72]) {
    int tid = threadIdx.x;
    int lane = tid & 63, wv = tid >> 6;
    int mw = (wv >> 1) * 32, nw = (wv & 1) * 32;
    int lr16 = lane & 15, g4 = lane >> 4;
    f32x4 acc[2][2] = {};
    for (int k0 = 0; k0 < K; k0 += 64) {
#pragma unroll
        for (int it = 0; it < 2; it++) {
            int idx = tid + it * 256;
            int r = idx >> 3, ch = idx & 7;
            uint4 av = *(const uint4*)(A + (size_t)(m0 + r) * K + k0 + ch * 8);
            *(uint4*)(&As[r][ch * 8]) = av;
            uint4 bv2 = *(const uint4*)(B + (size_t)(n0 + r) * K + k0 + ch * 8);
            *(uint4*)(&Bs[r][ch * 8]) = bv2;
        }
        __syncthreads();
#pragma unroll
        for (int ks = 0; ks < 2; ks++) {
            bf16x8 af[2], bfr[2];
#pragma unroll
            for (int i = 0; i < 2; i++) {
                af[i]  = *(const bf16x8*)(&As[mw + i * 16 + lr16][ks * 32 + g4 * 8]);
                bfr[i] = *(const bf16x8*)(&Bs[nw + i * 16 + lr16][ks * 32 + g4 * 8]);
            }
#pragma unroll
            for (int i = 0; i < 2; i++)
#pragma unroll
                for (int j = 0; j < 2; j++)
                    acc[i][j] = __builtin_amdgcn_mfma_f32_16x16x32_bf16(af[i], bfr[j], acc[i][j], 0, 0, 0);
        }
        __syncthreads();
    }
#pragma unroll
    for (int i = 0; i < 2; i++)
#pragma unroll
        for (int j = 0; j < 2; j++)
#pragma unroll
            for (int r2 = 0; r2 < 4; r2++) {
                int mm = m0 + mw + i * 16 + g4 * 4 + r2;
                int nn = n0 + nw + j * 16 + lr16;
                C[(size_t)mm * N + nn] = acc[i][j][r2] + (bias ? bias[nn] : 0.f);
            }
}

// ---------------- input projection GEMM (0-511) + round-weight prep (512-639) ----------------
__global__ __launch_bounds__(256) void k_xproj(
    const ushort* __restrict__ x_bf, const ushort* __restrict__ WihFB,
    const float* __restrict__ biasFB, float* __restrict__ Xpre,
    const float* __restrict__ Wg_hh, const float* __restrict__ Wr_hh,
    const float* __restrict__ W_Lr, const float* __restrict__ bg_hh,
    const float* __restrict__ br_hh,
    const float* __restrict__ Wg_ih, const float* __restrict__ Wr_ih,
    ushort* __restrict__ WhhGR, ushort* __restrict__ WLrAB, float* __restrict__ biasGR,
    float* __restrict__ WgihT, float* __restrict__ WrihT) {
    int bid = blockIdx.x;
    __shared__ __align__(16) ushort As[64][72];
    __shared__ __align__(16) ushort Bs[64][72];
    if (bid < 512) {
        int nt = bid & 31, mt = bid >> 5;
        gemm_tile(x_bf, WihFB, biasFB, Xpre, G2, KPAD, mt * 64, nt * 64, As, Bs);
        return;
    }
    const int stride = 128 * 256;
    int pid = (bid - 512) * 256 + threadIdx.x;
    for (int idx = pid; idx < GHW * H2c; idx += stride) {
        int r = idx >> 9, c = idx & 511;
        float v = (r < G3) ? Wg_hh[(size_t)r * H2c + c] : Wr_hh[(size_t)(r - G3) * H2c + c];
        WhhGR[idx] = b16rne(v);
    }
    for (int idx = pid; idx < G4 * H2c; idx += stride) {
        int r = idx >> 9, c = idx & 511;
        float v = (r < H2c) ? W_Lr[(size_t)r * (2 * H2c) + c]
                            : W_Lr[(size_t)(r - H2c) * (2 * H2c) + H2c + c];
        WLrAB[idx] = b16rne(v);
    }
    for (int idx = pid; idx < GHW; idx += stride)
        biasGR[idx] = (idx < G3) ? bg_hh[idx] : br_hh[idx - G3];
    for (int idx = pid; idx < NBIOc * G3; idx += stride) {
        int k = idx / G3, rj = idx - k * G3;
        WgihT[idx] = Wg_ih[(size_t)rj * NBIOc + k];
    }
    for (int idx = pid; idx < NLABc * G3; idx += stride) {
        int k = idx / G3, rj = idx - k * G3;
        WrihT[idx] = Wr_ih[(size_t)rj * NLABc + k];
    }
}

// ---------------- bidirectional masked LSTM (r11/r14-best: 8 blocks x 512 threads) ----------------
// Weight slice (256x256 bf16) in VGPRs (84 VGPR, no spill); Glds gate staging;
// 3 barriers/step. Tagged-u64 h exchange via relaxed agent atomics.
// Publish FIRST, Henc stores before barrier C (drain during barrier wait).
// r13 lesson: 1024-thread variant spills aw[] — keep 512.
// r15 lesson: partner-only polling cuts FETCH 11% but is time-neutral (latency-
// bound on straggler publish, not poll volume) and costs VGPR — keep full poll.
__global__ __launch_bounds__(512) void k_lstm_mfma(
    const float* __restrict__ Xpre, const float* __restrict__ WhhF,
    const float* __restrict__ WhhB, const float* __restrict__ mask,
    float* __restrict__ Henc, ushort* __restrict__ HencB,
    unsigned long long* __restrict__ hG) {
    const int blk = blockIdx.x;
    const int d = blk >> 2, q = blk & 3;
    const float* Whh = d ? WhhB : WhhF;
    const int tid = threadIdx.x;
    const int lane = tid & 63, wv = tid >> 6;
    const int lr16 = lane & 15, g4 = lane >> 4;

    __shared__ __align__(16) uint32_t hlds[2][8 * 136];
    __shared__ float Glds[256][9];

    bf16x8 aw[16];
#pragma unroll
    for (int jt2 = 0; jt2 < 2; jt2++) {
        int jt = wv * 2 + jt2;
        int lr = jt * 16 + lr16;
        int g = lr >> 6, jj = lr & 63;
        int R = g * 256 + q * 64 + jj;
        const float* wr = Whh + (size_t)R * 256;
#pragma unroll
        for (int kt = 0; kt < 8; kt++) {
            int k0 = kt * 32 + g4 * 8;
            float4 f0 = *(const float4*)(wr + k0);
            float4 f1 = *(const float4*)(wr + k0 + 4);
            bf16x8 a;
            a[0] = (short)b16rne(f0.x); a[1] = (short)b16rne(f0.y);
            a[2] = (short)b16rne(f0.z); a[3] = (short)b16rne(f0.w);
            a[4] = (short)b16rne(f1.x); a[5] = (short)b16rne(f1.y);
            a[6] = (short)b16rne(f1.z); a[7] = (short)b16rne(f1.w);
            aw[jt2 * 8 + kt] = a;
        }
    }

    const int jj_t = tid & 63, b_t = tid >> 6;
    float hval = 0.f, cval = 0.f;
    const int bcol = lane & 15;
    const int bb = lane & 7;
    const int u1 = tid + 512;

    for (int s = 0; s < Ln; s++) {
        const int t = d ? (Ln - 1 - s) : s;

        const float* xrow = Xpre + ((size_t)(b_t * Ln + t)) * G2 + d * G4 + q * 64 + jj_t;
        float xg0 = xrow[0], xg1 = xrow[256], xg2 = xrow[512], xg3 = xrow[768];
        float mval = mask[b_t * Ln + t];

        const unsigned long long* slot = hG + ((size_t)(s & 1) * 2 + d) * 1024;
        unsigned long long ea, eb;
        do {
            ea = __hip_atomic_load(slot + tid, __ATOMIC_RELAXED, __HIP_MEMORY_SCOPE_AGENT);
            eb = __hip_atomic_load(slot + u1,  __ATOMIC_RELAXED, __HIP_MEMORY_SCOPE_AGENT);
        } while ((unsigned)(ea >> 32) != (unsigned)s || (unsigned)(eb >> 32) != (unsigned)s);
        uint32_t* hb = hlds[s & 1];
        hb[(tid >> 7) * 136 + (tid & 127)] = (uint32_t)ea;
        hb[(u1 >> 7) * 136 + (u1 & 127)]  = (uint32_t)eb;
        __syncthreads();                          // A: stage-write -> ds_read

        bf16x8 bv[8];
#pragma unroll
        for (int kt = 0; kt < 8; kt++)
            bv[kt] = *(const bf16x8*)(&hb[bb * 136 + kt * 16 + g4 * 4]);

        f32x4 acc0 = {0.f, 0.f, 0.f, 0.f}, acc1 = {0.f, 0.f, 0.f, 0.f};
#pragma unroll
        for (int kt = 0; kt < 8; kt++) {
            acc0 = __builtin_amdgcn_mfma_f32_16x16x32_bf16(aw[kt], bv[kt], acc0, 0, 0, 0);
            acc1 = __builtin_amdgcn_mfma_f32_16x16x32_bf16(aw[8 + kt], bv[kt], acc1, 0, 0, 0);
        }

        if (bcol < 8) {
            int lrb0 = (wv * 2 + 0) * 16 + g4 * 4;
            int lrb1 = (wv * 2 + 1) * 16 + g4 * 4;
#pragma unroll
            for (int r2 = 0; r2 < 4; r2++) Glds[lrb0 + r2][bcol] = acc0[r2];
#pragma unroll
            for (int r2 = 0; r2 < 4; r2++) Glds[lrb1 + r2][bcol] = acc1[r2];
        }
        __syncthreads();                          // B: Glds write -> read

        float iv = sigf(xg0 + Glds[jj_t][b_t]);
        float fv = sigf(xg1 + Glds[64 + jj_t][b_t]);
        float gv = tanhf(xg2 + Glds[128 + jj_t][b_t]);
        float ov = sigf(xg3 + Glds[192 + jj_t][b_t]);
        float cn = fv * cval + iv * gv;
        float hn = ov * tanhf(cn);
        float hv = mval * hn + (1.f - mval) * hval;
        cval = mval * cn + (1.f - mval) * cval;
        hval = hv;

        // publish FIRST (critical path), then Henc stores (drain during barrier C)
        int hbits = (int)b16rne(hv);
        int pbits = __shfl_xor(hbits, 1);
        if ((jj_t & 1) == 0) {
            uint32_t dataw = ((uint32_t)hbits & 0xFFFFu) | ((uint32_t)pbits << 16);
            unsigned long long word = ((unsigned long long)(unsigned)(s + 1) << 32) | dataw;
            __hip_atomic_store(hG + ((size_t)((s + 1) & 1) * 2 + d) * 1024 +
                                   b_t * 128 + q * 32 + (jj_t >> 1),
                               word, __ATOMIC_RELAXED, __HIP_MEMORY_SCOPE_AGENT);
        }
        float ho = hv * mval;
        size_t hidx = ((size_t)(b_t * Ln + t)) * H2c + d * Hc + q * 64 + jj_t;
        Henc[hidx] = ho;
        HencB[hidx] = b16rne(ho);
        __syncthreads();                          // C: drain publishes before next poll
    }
}

// ---------------- mega: gh GEMM (0..nGh) | pairC GEMM (+256) | proj9 (+256) ----------------
__global__ __launch_bounds__(256) void k_mega(
    int nGh,
    const ushort* __restrict__ Agh, const ushort* __restrict__ Bgh,
    const float* __restrict__ biasGh, float* __restrict__ Cgh,
    const ushort* __restrict__ Apc, const ushort* __restrict__ Bpc,
    float* __restrict__ Cpc,
    const float* __restrict__ Hp9, const float* __restrict__ W9,
    const float* __restrict__ b9, float* __restrict__ out9) {
    int bid = blockIdx.x;
    __shared__ __align__(16) ushort As[64][72];
    __shared__ __align__(16) ushort Bs[64][72];
    if (bid < nGh) {
        int nt = bid % 48, mt = bid / 48;
        gemm_tile(Agh, Bgh, biasGh, Cgh, GHW, H2c, mt * 64, nt * 64, As, Bs);
    } else if (bid < nGh + 256) {
        int b2 = bid - nGh;
        int nt = b2 & 15, mt = b2 >> 4;
        gemm_tile(Apc, Bpc, nullptr, Cpc, G4, H2c, mt * 64, nt * 64, As, Bs);
    } else {
        int b3 = bid - nGh - 256;
        int lane = threadIdx.x & 63, wvv = threadIdx.x >> 6;
        int row = b3 * 4 + wvv;
        const float4* h4 = (const float4*)(Hp9 + (size_t)row * H2c + lane * 8);
        float4 h0 = h4[0], h1 = h4[1];
        float acc[NBIOc];
#pragma unroll
        for (int k = 0; k < NBIOc; k++) {
            const float4* w4 = (const float4*)(W9 + (size_t)k * H2c + lane * 8);
            float4 w0 = w4[0], w1 = w4[1];
            acc[k] = h0.x * w0.x + h0.y * w0.y + h0.z * w0.z + h0.w * w0.w +
                     h1.x * w1.x + h1.y * w1.y + h1.z * w1.z + h1.w * w1.w;
        }
#pragma unroll
        for (int off = 32; off >= 1; off >>= 1)
#pragma unroll
            for (int k = 0; k < NBIOc; k++) acc[k] += __shfl_down(acc[k], off);
        if (lane == 0) {
#pragma unroll
            for (int k = 0; k < NBIOc; k++) out9[(size_t)row * NBIOc + k] = acc[k] + b9[k];
        }
    }
}

// ---------------- fused pairmax + double GRU per row m (transposed ih weights) ----------------
__global__ __launch_bounds__(128) void k_pairgru(
    const float* __restrict__ Cp, const float* __restrict__ bL,
    const float* __restrict__ WCr, const float* __restrict__ bCr,
    const float* __restrict__ mask, const float* __restrict__ cg,
    const float* __restrict__ gh,
    const float* __restrict__ WgihT, const float* __restrict__ bg_ih,
    const float* __restrict__ WrihT, const float* __restrict__ br_ih,
    const float* __restrict__ hprev,
    float* __restrict__ Hg_out, float* __restrict__ Hcb_out,
    ushort* __restrict__ Hrb_out, ushort* __restrict__ Hcbb_out) {
    int m = blockIdx.x;
    int b = m >> 7;
    __shared__ __align__(16) float As[H2c];
    __shared__ __align__(16) float Ws[NLABc][H2c];
    __shared__ float red[NLABc][128];
    __shared__ float pCr_s[NLABc];
    int tid = threadIdx.x;
    for (int i = tid; i < H2c; i += 128) As[i] = Cp[(size_t)m * G4 + i] + bL[i];
    for (int i = tid; i < NLABc * H2c; i += 128) Ws[i / H2c][i % H2c] = WCr[i];
    __syncthreads();
    {
        int t = tid;
        float m3 = mask[m] * mask[b * Ln + t];
        float outv[NLABc];
        if (m3 > 0.f) {
            float4 acc[NLABc];
#pragma unroll
            for (int k = 0; k < NLABc; k++) acc[k] = make_float4(0.f, 0.f, 0.f, 0.f);
            const float4* B4 = (const float4*)(Cp + (size_t)(b * Ln + t) * G4 + H2c);
            const float4* A4 = (const float4*)As;
            for (int qq = 0; qq < H2c / 4; qq++) {
                float4 a = A4[qq], bb = B4[qq];
                float4 e;
                e.x = fmaxf(a.x + bb.x, 0.f);
                e.y = fmaxf(a.y + bb.y, 0.f);
                e.z = fmaxf(a.z + bb.z, 0.f);
                e.w = fmaxf(a.w + bb.w, 0.f);
#pragma unroll
                for (int k = 0; k < NLABc; k++) {
                    float4 w = *(const float4*)(&Ws[k][qq * 4]);
                    acc[k].x += e.x * w.x; acc[k].y += e.y * w.y;
                    acc[k].z += e.z * w.z; acc[k].w += e.w * w.w;
                }
            }
#pragma unroll
            for (int k = 0; k < NLABc; k++)
                outv[k] = sigf(acc[k].x + acc[k].y + acc[k].z + acc[k].w + bCr[k]);
        } else {
#pragma unroll
            for (int k = 0; k < NLABc; k++) outv[k] = NEGc;
        }
#pragma unroll
        for (int k = 0; k < NLABc; k++) red[k][tid] = outv[k];
    }
    __syncthreads();
    for (int off = 64; off >= 1; off >>= 1) {
        if (tid < off) {
#pragma unroll
            for (int k = 0; k < NLABc; k++) red[k][tid] = fmaxf(red[k][tid], red[k][tid + off]);
        }
        __syncthreads();
    }
    if (tid < NLABc) pCr_s[tid] = red[tid][0];
    __syncthreads();

    float v[NBIOc], mx = -3.4e38f;
#pragma unroll
    for (int k = 0; k < NBIOc; k++) { v[k] = cg[m * NBIOc + k]; mx = fmaxf(mx, v[k]); }
    float ssum = 0.f;
#pragma unroll
    for (int k = 0; k < NBIOc; k++) { v[k] = __expf(v[k] - mx); ssum += v[k]; }
    float inv = 1.f / ssum;
#pragma unroll
    for (int k = 0; k < NBIOc; k++) v[k] *= inv;

    const float* g1b = gh + (size_t)m * GHW;
#pragma unroll
    for (int u = 0; u < 4; u++) {
        int j = tid + u * 128;
        size_t i = (size_t)m * H2c + j;

        float gr = bg_ih[j], gz = bg_ih[H2c + j], gn = bg_ih[2 * H2c + j];
#pragma unroll
        for (int k = 0; k < NBIOc; k++) {
            float pv = v[k];
            gr += WgihT[k * G3 + j] * pv;
            gz += WgihT[k * G3 + H2c + j] * pv;
            gn += WgihT[k * G3 + 2 * H2c + j] * pv;
        }
        float hp = hprev[i];
        float r1 = sigf(gr + g1b[j]);
        float z1 = sigf(gz + g1b[H2c + j]);
        float n1 = tanhf(gn + r1 * g1b[2 * H2c + j]);
        float hg = (1.f - z1) * n1 + z1 * hp;

        float rr = br_ih[j], rz = br_ih[H2c + j], rn = br_ih[2 * H2c + j];
#pragma unroll
        for (int k = 0; k < NLABc; k++) {
            float pv = pCr_s[k];
            rr += WrihT[k * G3 + j] * pv;
            rz += WrihT[k * G3 + H2c + j] * pv;
            rn += WrihT[k * G3 + 2 * H2c + j] * pv;
        }
        const float* g2b = g1b + G3;
        float r2 = sigf(rr + g2b[j]);
        float z2 = sigf(rz + g2b[H2c + j]);
        float n2 = tanhf(rn + r2 * g2b[2 * H2c + j]);
        float hr = (1.f - z2) * n2 + z2 * hp;

        float hc = hp + hr + hg;
        Hg_out[i] = hg;
        Hcb_out[i] = hc;
        Hrb_out[i] = b16rne(hr);
        Hcbb_out[i] = b16rne(hc);
    }
}

// ---------------- final: pairfull (blocks 0-1023) + log_softmax (blocks 1024-1031) ----------------
__global__ __launch_bounds__(128) void k_final_out(
    const float* __restrict__ Cp, const float* __restrict__ bL,
    const float* __restrict__ WCr, const float* __restrict__ bCr,
    const float* __restrict__ mask, const float* __restrict__ cg,
    float* __restrict__ outp) {
    int bid = blockIdx.x;
    int tid = threadIdx.x;
    if (bid >= Bn * Ln) {
        int r = (bid - Bn * Ln) * 128 + tid;
        float v[NBIOc], mx = -3.4e38f;
#pragma unroll
        for (int k = 0; k < NBIOc; k++) { v[k] = cg[r * NBIOc + k]; mx = fmaxf(mx, v[k]); }
        float s = 0.f;
#pragma unroll
        for (int k = 0; k < NBIOc; k++) s += __expf(v[k] - mx);
        float lse = mx + __logf(s);
        float m = mask[r];
#pragma unroll
        for (int k = 0; k < NBIOc; k++) outp[r * NBIOc + k] = (v[k] - lse) * m;
        return;
    }
    int bs = bid;
    int b = bs >> 7;
    __shared__ __align__(16) float As[H2c];
    __shared__ __align__(16) float Ws[NLABc][H2c];
    for (int i = tid; i < H2c; i += 128) As[i] = Cp[(size_t)bs * G4 + i] + bL[i];
    for (int i = tid; i < NLABc * H2c; i += 128) Ws[i / H2c][i % H2c] = WCr[i];
    __syncthreads();
    int t = tid;
    float m3 = mask[bs] * mask[b * Ln + t];
    float outv[NLABc];
    if (m3 > 0.f) {
        float4 acc[NLABc];
#pragma unroll
        for (int k = 0; k < NLABc; k++) acc[k] = make_float4(0.f, 0.f, 0.f, 0.f);
        const float4* B4 = (const float4*)(Cp + (size_t)(b * Ln + t) * G4 + H2c);
        const float4* A4 = (const float4*)As;
        for (int qq = 0; qq < H2c / 4; qq++) {
            float4 a = A4[qq], bb = B4[qq];
            float4 e;
            e.x = fmaxf(a.x + bb.x, 0.f);
            e.y = fmaxf(a.y + bb.y, 0.f);
            e.z = fmaxf(a.z + bb.z, 0.f);
            e.w = fmaxf(a.w + bb.w, 0.f);
#pragma unroll
            for (int k = 0; k < NLABc; k++) {
                float4 w = *(const float4*)(&Ws[k][qq * 4]);
                acc[k].x += e.x * w.x; acc[k].y += e.y * w.y;
                acc[k].z += e.z * w.z; acc[k].w += e.w * w.w;
            }
        }
#pragma unroll
        for (int k = 0; k < NLABc; k++)
            outv[k] = sigf(acc[k].x + acc[k].y + acc[k].z + acc[k].w + bCr[k]);
    } else {
#pragma unroll
        for (int k = 0; k < NLABc; k++) outv[k] = 0.f;
    }
    size_t base = (size_t)(Bn * Ln * NBIOc) + ((size_t)bs * Ln + t) * NLABc;
#pragma unroll
    for (int k = 0; k < NLABc; k++) outp[base + k] = outv[k];
}

extern "C" void kernel_launch(void* const* d_in, const int* in_sizes, int n_in,
                              void* d_out, int out_size, void* d_ws, size_t ws_size,
                              hipStream_t stream) {
    const int*   tok   = (const int*)d_in[0];
    const int*   pos   = (const int*)d_in[1];
    const float* mask  = (const float*)d_in[2];
    const float* emb   = (const float*)d_in[3];
    const float* pemb  = (const float*)d_in[4];
    const float* WihF  = (const float*)d_in[5];
    const float* WhhF  = (const float*)d_in[6];
    const float* bF    = (const float*)d_in[7];
    const float* WihB  = (const float*)d_in[8];
    const float* WhhB  = (const float*)d_in[9];
    const float* bB    = (const float*)d_in[10];
    const float* Wg_ih = (const float*)d_in[11];
    const float* Wg_hh = (const float*)d_in[12];
    const float* bg_ih = (const float*)d_in[13];
    const float* bg_hh = (const float*)d_in[14];
    const float* Wr_ih = (const float*)d_in[15];
    const float* Wr_hh = (const float*)d_in[16];
    const float* br_ih = (const float*)d_in[17];
    const float* br_hh = (const float*)d_in[18];
    const float* W_Lr  = (const float*)d_in[19];
    const float* b_Lr  = (const float*)d_in[20];
    const float* W_Cr  = (const float*)d_in[21];
    const float* b_Cr  = (const float*)d_in[22];
    const float* W_Cg  = (const float*)d_in[23];
    const float* b_Cg  = (const float*)d_in[24];

    float* outp = (float*)d_out;
    float* ws = (float*)d_ws;

    unsigned long long* hG = (unsigned long long*)ws;
    size_t off = 8192;
    auto alloc = [&](size_t n) { off = (off + 3) & ~(size_t)3; float* p = ws + off; off += n; return p; };
    auto allocU = [&](size_t n_us) { off = (off + 3) & ~(size_t)3; ushort* p = (ushort*)(ws + off); off += (n_us + 1) / 2; return p; };

    float* R1 = alloc((size_t)G4 * GHW);
    float* Xpre = R1;
    float* gh   = R1;
    ushort* WihFB_bf = (ushort*)(R1 + (size_t)G4 * G2);
    ushort* x_bf     = (ushort*)(R1 + (size_t)G4 * G2 + 393216);
    float*  biasFB   = R1 + (size_t)G4 * G2 + 393216 + 196608;

    float*  pairC    = alloc((size_t)G4 * G4);
    ushort* WhhGR_bf = allocU((size_t)GHW * H2c);
    ushort* WLrAB_bf = allocU((size_t)G4 * H2c);
    float*  biasGR   = alloc(GHW);
    float*  WgihT    = alloc((size_t)NBIOc * G3);
    float*  WrihT    = alloc((size_t)NLABc * G3);
    float*  Henc     = alloc((size_t)Bn * Ln * H2c);
    ushort* Henc_bf  = allocU((size_t)Bn * Ln * H2c);
    float*  Hg       = alloc((size_t)Bn * Ln * H2c);
    float*  Hcb      = alloc((size_t)Bn * Ln * H2c);
    ushort* Hr_bf    = allocU((size_t)Bn * Ln * H2c);
    ushort* Hcb_bf   = allocU((size_t)Bn * Ln * H2c);
    float*  cg       = alloc((size_t)Bn * Ln * NBIOc);
    (void)ws_size; (void)in_sizes; (void)n_in; (void)out_size;

    // --- prep0: embed + input-proj weights + zero hG (agent-scope stores) ---
    {
        int total = Bn * Ln * KPAD + G2 * KPAD + G2 + 8192;
        k_prep0<<<(total + 255) / 256, 256, 0, stream>>>(
            tok, pos, emb, pemb, WihF, WihB, bF, bB, x_bf, WihFB_bf, biasFB,
            (uint32_t*)hG);
    }

    // --- input projection GEMM + concurrent round-weight prep ---
    k_xproj<<<640, 256, 0, stream>>>(x_bf, WihFB_bf, biasFB, Xpre,
                                     Wg_hh, Wr_hh, W_Lr, bg_hh, br_hh,
                                     Wg_ih, Wr_ih,
                                     WhhGR_bf, WLrAB_bf, biasGR, WgihT, WrihT);

    // --- bidirectional LSTM: 8 blocks x 512 threads ---
    k_lstm_mfma<<<8, 512, 0, stream>>>(Xpre, WhhF, WhhB, mask, Henc, Henc_bf, hG);

    // --- message-passing rounds ---
    const float*  Hgs    = Henc;
    const ushort* Hrs_bf = Henc_bf;
    const float*  Hcs    = Henc;
    const ushort* Hcs_bf = Henc_bf;
    for (int r = 0; r < 2; r++) {
        k_mega<<<768 + 512, 256, 0, stream>>>(768,
            Hcs_bf, WhhGR_bf, biasGR, gh,
            Hrs_bf, WLrAB_bf, pairC,
            Hgs, W_Cg, b_Cg, cg);
        k_pairgru<<<Bn * Ln, 128, 0, stream>>>(
            pairC, b_Lr, W_Cr, b_Cr, mask, cg, gh,
            WgihT, bg_ih, WrihT, br_ih, Hcs,
            Hg, Hcb, Hr_bf, Hcb_bf);
        Hgs = Hg; Hrs_bf = Hr_bf; Hcs = Hcb; Hcs_bf = Hcb_bf;
    }

    // --- final outputs: pairC GEMM + proj9, then pairfull + logsoftmax ---
    k_mega<<<512, 256, 0, stream>>>(0,
        nullptr, nullptr, nullptr, nullptr,
        Hrs_bf, WLrAB_bf, pairC,
        Hgs, W_Cg, b_Cg, cg);
    k_final_out<<<Bn * Ln + 8, 128, 0, stream>>>(pairC, b_Lr, W_Cr, b_Cr, mask, cg, outp);
}